// Round 3
// baseline (344.367 us; speedup 1.0000x reference)
//
#include <hip/hip_runtime.h>
#include <hip/hip_bf16.h>
#include <stdint.h>

#define D 1024
#define NSUP 256
#define ROWS 16384   // 4*4096
#define MB 32        // rows per block
#define LTHREADS 512
#define LGRID (ROWS / MB)   // 512 blocks -> 2 blocks/CU

typedef __attribute__((__ext_vector_type__(8))) __bf16 bf16x8;
typedef __attribute__((__ext_vector_type__(4))) float f32x4;
typedef __attribute__((__ext_vector_type__(4))) uint32_t u32x4;

#define MFMA16(a, b, c) __builtin_amdgcn_mfma_f32_16x16x32_bf16((a), (b), (c), 0, 0, 0)

// XOR swizzle: permutes 16B slots within a 128B window keyed by row&7.
__device__ __forceinline__ int swz(int row, int byte) { return byte ^ ((row & 7) << 4); }

__global__ void cast_k_kernel(const float* __restrict__ K, __bf16* __restrict__ Kb) {
    int i = (blockIdx.x * 256 + threadIdx.x) * 4;
    float4 v = *(const float4*)(K + i);
    __bf16 o[4] __attribute__((aligned(8)));
    o[0] = (__bf16)v.x; o[1] = (__bf16)v.y; o[2] = (__bf16)v.z; o[3] = (__bf16)v.w;
    *(uint2*)(Kb + i) = *(const uint2*)o;
}

// V [4][256][1024] f32 -> Vt [4][1024][256] bf16
__global__ void transpose_v_kernel(const float* __restrict__ V, __bf16* __restrict__ Vt) {
    __shared__ __bf16 tile[64][72];
    int l = blockIdx.z;
    int d0 = blockIdx.x * 64, n0 = blockIdx.y * 64;
    const float* Vl = V + (size_t)l * NSUP * D;
    __bf16* Vtl = Vt + (size_t)l * D * NSUP;
    for (int j = 0; j < 16; ++j) {
        int idx = j * 256 + threadIdx.x;
        int n_l = idx >> 6, d_l = idx & 63;
        tile[d_l][n_l] = (__bf16)Vl[(size_t)(n0 + n_l) * D + d0 + d_l];
    }
    __syncthreads();
    for (int j = 0; j < 16; ++j) {
        int idx = j * 256 + threadIdx.x;
        int d_l = idx >> 6, n_l = idx & 63;
        Vtl[(size_t)(d0 + d_l) * NSUP + n0 + n_l] = tile[d_l][n_l];
    }
}

// One fused CleanUpKV layer.
//  - IN_F32:  input is raw f32 x -> fused row-norm pre-pass + scale-on-stage.
//    else:    input is ALREADY-NORMALIZED bf16 hn -> pure-copy staging via
//             global_load_lds (pre-swizzled source, linear LDS dest).
//  - OUT_F32: write raw f32 result (final layer). else: write NORMALIZED bf16
//             (rn computed in epilogue), staged through LDS for dense stores.
// Block: 512 thr (8 waves), 32 rows. Wave cg owns score cols [cg*32,+32) and
// PV d-cols [cg*128,+128).
template<bool IN_F32, bool OUT_F32>
__global__ __launch_bounds__(LTHREADS, 4)
void layer_kernel(const void* __restrict__ h_in, void* __restrict__ h_out,
                  const __bf16* __restrict__ Kb, const __bf16* __restrict__ Vt) {
    const int tid = threadIdx.x;
    const int lane = tid & 63;
    const int cg = tid >> 6;            // wave 0..7
    const int llo = lane & 15, lhi = lane >> 4;
    const int row0 = blockIdx.x * MB;

    // [0,16K) hn buf0 | [16K,32K) hn buf1 | [32K,48K) w
    // epilogue reuses [0,32K) as [32 rows][1024B] staging
    __shared__ __align__(16) char pool[49152];
    __shared__ float red1[MB][8];
    __shared__ float red2[MB][8];
    __shared__ float rnin_s[MB];

    char* wbuf = pool + 32768;

    // ---- layer-1 only: fused row-norm pre-pass over f32 x ----
    if constexpr (IN_F32) {
        const float4* x4 = (const float4*)h_in;
        #pragma unroll
        for (int rr = 0; rr < 4; ++rr) {
            int row = cg * 4 + rr;
            const float4* p = x4 + (size_t)(row0 + row) * 256;
            float s = 0.f;
            #pragma unroll
            for (int j = 0; j < 4; ++j) {
                float4 v = p[j * 64 + lane];
                s += v.x * v.x + v.y * v.y + v.z * v.z + v.w * v.w;
            }
            #pragma unroll
            for (int off = 1; off < 64; off <<= 1) s += __shfl_xor(s, off);
            if (lane == 0) rnin_s[row] = 1.f / (sqrtf(s) + 1e-9f);
        }
        __syncthreads();
    }

    // ---- staging: one 32x256-col chunk (16KB bf16) into buffer dc&1 ----
    auto stage = [&](int dc) {
        char* hb = pool + (dc & 1) * 16384;
        if constexpr (IN_F32) {
            int srow = tid >> 4;
            int sd = (tid & 15) * 16;  // elem offset in chunk
            const float4* p = (const float4*)((const float*)h_in + (size_t)(row0 + srow) * D + dc * 256 + sd);
            float rn = rnin_s[srow];
            __bf16 tmp[16] __attribute__((aligned(16)));
            #pragma unroll
            for (int q = 0; q < 4; ++q) {
                float4 v = p[q];
                tmp[4 * q + 0] = (__bf16)(v.x * rn);
                tmp[4 * q + 1] = (__bf16)(v.y * rn);
                tmp[4 * q + 2] = (__bf16)(v.z * rn);
                tmp[4 * q + 3] = (__bf16)(v.w * rn);
            }
            char* base = hb + srow * 512;
            *(bf16x8*)(base + swz(srow, sd * 2))      = *(const bf16x8*)(tmp);
            *(bf16x8*)(base + swz(srow, sd * 2 + 16)) = *(const bf16x8*)(tmp + 8);
        } else {
            #pragma unroll
            for (int c = 0; c < 2; ++c) {
                int row = c * 16 + (tid >> 5);
                int seg = tid & 31;
                // pre-swizzled global source, linear LDS dest (wave base + lane*16)
                const char* g = (const char*)h_in + (size_t)(row0 + row) * 2048 + (size_t)dc * 512
                                + swz(row, seg * 16);
                char* l = hb + row * 512 + seg * 16;
                __builtin_amdgcn_global_load_lds(
                    (const __attribute__((address_space(1))) uint32_t*)g,
                    (__attribute__((address_space(3))) uint32_t*)l, 16, 0, 0);
            }
        }
    };

    // ---------- Phase A: scores[32x256] = hn @ K^T ----------
    f32x4 acc[2][2];
    #pragma unroll
    for (int rf = 0; rf < 2; ++rf)
        #pragma unroll
        for (int cf = 0; cf < 2; ++cf)
            acc[rf][cf] = (f32x4){0.f, 0.f, 0.f, 0.f};

    stage(0);
    __syncthreads();
    #pragma unroll 1
    for (int dc = 0; dc < 4; ++dc) {
        if (dc < 3) stage(dc + 1);            // prefetch into other buffer
        const char* hb = pool + (dc & 1) * 16384;
        #pragma unroll
        for (int k = 0; k < 8; ++k) {
            bf16x8 a0 = *(const bf16x8*)(hb + llo * 512 + swz(llo, k * 64 + lhi * 16));
            bf16x8 a1 = *(const bf16x8*)(hb + (16 + llo) * 512 + swz(16 + llo, k * 64 + lhi * 16));
            #pragma unroll
            for (int cf = 0; cf < 2; ++cf) {
                bf16x8 b = *(const bf16x8*)(Kb + (size_t)(cg * 32 + cf * 16 + llo) * D
                                            + dc * 256 + k * 32 + lhi * 8);
                acc[0][cf] = MFMA16(a0, b, acc[0][cf]);
                acc[1][cf] = MFMA16(a1, b, acc[1][cf]);
            }
        }
        __syncthreads();   // drains prefetch + protects dbuf reuse
    }

    // ---------- Phase B: softmax over 256 cols ----------
    float rmax[2][4];
    #pragma unroll
    for (int rf = 0; rf < 2; ++rf)
        #pragma unroll
        for (int r = 0; r < 4; ++r) {
            float m = fmaxf(acc[rf][0][r], acc[rf][1][r]);
            #pragma unroll
            for (int off = 1; off < 16; off <<= 1) m = fmaxf(m, __shfl_xor(m, off));
            rmax[rf][r] = m;
            if (llo == 0) red1[rf * 16 + lhi * 4 + r][cg] = m;
        }
    __syncthreads();
    float rsum[2][4];
    #pragma unroll
    for (int rf = 0; rf < 2; ++rf)
        #pragma unroll
        for (int r = 0; r < 4; ++r) {
            int row = rf * 16 + lhi * 4 + r;
            f32x4 m0 = *(const f32x4*)&red1[row][0];
            f32x4 m1 = *(const f32x4*)&red1[row][4];
            float m = fmaxf(fmaxf(fmaxf(m0[0], m0[1]), fmaxf(m0[2], m0[3])),
                            fmaxf(fmaxf(m1[0], m1[1]), fmaxf(m1[2], m1[3])));
            float s = 0.f;
            #pragma unroll
            for (int cf = 0; cf < 2; ++cf) {
                float e = exp2f((acc[rf][cf][r] - m) * 1.44269504f);
                acc[rf][cf][r] = e;
                s += e;
            }
            #pragma unroll
            for (int off = 1; off < 16; off <<= 1) s += __shfl_xor(s, off);
            rsum[rf][r] = s;
            if (llo == 0) red2[row][cg] = s;
        }
    __syncthreads();
    #pragma unroll
    for (int rf = 0; rf < 2; ++rf)
        #pragma unroll
        for (int r = 0; r < 4; ++r) {
            int row = rf * 16 + lhi * 4 + r;
            f32x4 s0 = *(const f32x4*)&red2[row][0];
            f32x4 s1 = *(const f32x4*)&red2[row][4];
            float s = (s0[0] + s0[1] + s0[2] + s0[3]) + (s1[0] + s1[1] + s1[2] + s1[3]);
            float inv = 1.f / s;
            #pragma unroll
            for (int cf = 0; cf < 2; ++cf) {
                int col = cg * 32 + cf * 16 + llo;
                *(__bf16*)(wbuf + row * 512 + swz(row, col * 2)) = (__bf16)(acc[rf][cf][r] * inv);
            }
        }
    __syncthreads();

    // ---------- Phase C: out[32x1024] = w @ V ----------
    f32x4 acc2[2][8];
    #pragma unroll
    for (int rf = 0; rf < 2; ++rf)
        #pragma unroll
        for (int cf = 0; cf < 8; ++cf)
            acc2[rf][cf] = (f32x4){0.f, 0.f, 0.f, 0.f};

    #pragma unroll
    for (int k = 0; k < 8; ++k) {
        bf16x8 a0 = *(const bf16x8*)(wbuf + llo * 512 + swz(llo, k * 64 + lhi * 16));
        bf16x8 a1 = *(const bf16x8*)(wbuf + (16 + llo) * 512 + swz(16 + llo, k * 64 + lhi * 16));
        #pragma unroll
        for (int cf = 0; cf < 8; ++cf) {
            bf16x8 b = *(const bf16x8*)(Vt + (size_t)(cg * 128 + cf * 16 + llo) * NSUP
                                        + k * 32 + lhi * 8);
            acc2[0][cf] = MFMA16(a0, b, acc2[0][cf]);
            acc2[1][cf] = MFMA16(a1, b, acc2[1][cf]);
        }
    }

    // ---------- Epilogue ----------
    if constexpr (OUT_F32) {
        float* outp = (float*)h_out;
        #pragma unroll
        for (int rf = 0; rf < 2; ++rf)
            #pragma unroll
            for (int cf = 0; cf < 8; ++cf) {
                int d = cg * 128 + cf * 16 + llo;
                #pragma unroll
                for (int r = 0; r < 4; ++r) {
                    int row = rf * 16 + lhi * 4 + r;
                    outp[(size_t)(row0 + row) * D + d] = acc2[rf][cf][r];
                }
            }
    } else {
        // next-layer row norms from our own output, then write NORMALIZED bf16
        float rnv[2][4];
        #pragma unroll
        for (int rf = 0; rf < 2; ++rf)
            #pragma unroll
            for (int r = 0; r < 4; ++r) {
                float s = 0.f;
                #pragma unroll
                for (int cf = 0; cf < 8; ++cf) s += acc2[rf][cf][r] * acc2[rf][cf][r];
                #pragma unroll
                for (int off = 1; off < 16; off <<= 1) s += __shfl_xor(s, off);
                if (llo == 0) red2[rf * 16 + lhi * 4 + r][cg] = s;
            }
        __syncthreads();
        #pragma unroll
        for (int rf = 0; rf < 2; ++rf)
            #pragma unroll
            for (int r = 0; r < 4; ++r) {
                int row = rf * 16 + lhi * 4 + r;
                f32x4 s0 = *(const f32x4*)&red2[row][0];
                f32x4 s1 = *(const f32x4*)&red2[row][4];
                float ss = (s0[0] + s0[1] + s0[2] + s0[3]) + (s1[0] + s1[1] + s1[2] + s1[3]);
                rnv[rf][r] = 1.f / (sqrtf(ss) + 1e-9f);
            }
        const int myhalf = cg >> 2;
        char* epi = pool;   // 32KB: [32 rows][1024B], swizzled
        #pragma unroll 1
        for (int hh = 0; hh < 2; ++hh) {
            if (myhalf == hh) {
                #pragma unroll
                for (int rf = 0; rf < 2; ++rf)
                    #pragma unroll
                    for (int cf = 0; cf < 8; ++cf) {
                        int dcol = (cg & 3) * 128 + cf * 16 + llo;
                        #pragma unroll
                        for (int r = 0; r < 4; ++r) {
                            int row = rf * 16 + lhi * 4 + r;
                            *(__bf16*)(epi + row * 1024 + swz(row, dcol * 2)) =
                                (__bf16)(acc2[rf][cf][r] * rnv[rf][r]);
                        }
                    }
            }
            __syncthreads();
            {
                int row = tid >> 4;
                #pragma unroll
                for (int j = 0; j < 4; ++j) {
                    int seg = (tid & 15) + 16 * j;
                    u32x4 v = *(const u32x4*)(epi + row * 1024 + swz(row, seg * 16));
                    *(u32x4*)((char*)h_out + (size_t)(row0 + row) * 2048 + hh * 1024 + seg * 16) = v;
                }
            }
            __syncthreads();
        }
    }
}

extern "C" void kernel_launch(void* const* d_in, const int* in_sizes, int n_in,
                              void* d_out, int out_size, void* d_ws, size_t ws_size,
                              hipStream_t stream) {
    const float* x = (const float*)d_in[0];
    const float* keys = (const float*)d_in[1];
    const float* values = (const float*)d_in[2];
    float* out = (float*)d_out;

    char* ws = (char*)d_ws;
    __bf16* h  = (__bf16*)(ws);                 // 16384*1024*2 = 33554432 B (normalized hn)
    __bf16* Kb = (__bf16*)(ws + 33554432);      // 4*256*1024*2 = 2097152 B
    __bf16* Vt = (__bf16*)(ws + 35651584);      // 4*1024*256*2 = 2097152 B

    cast_k_kernel<<<1024, 256, 0, stream>>>(keys, Kb);
    transpose_v_kernel<<<dim3(16, 4, 4), 256, 0, stream>>>(values, Vt);

    const int LS = NSUP * D;
    layer_kernel<true,  false><<<LGRID, LTHREADS, 0, stream>>>(x, h, Kb,          Vt);
    layer_kernel<false, false><<<LGRID, LTHREADS, 0, stream>>>(h, h, Kb + LS,     Vt + LS);
    layer_kernel<false, false><<<LGRID, LTHREADS, 0, stream>>>(h, h, Kb + 2 * LS, Vt + 2 * LS);
    layer_kernel<false, true ><<<LGRID, LTHREADS, 0, stream>>>(h, out, Kb + 3 * LS, Vt + 3 * LS);
}